// Round 2
// baseline (4986.645 us; speedup 1.0000x reference)
//
#include <hip/hip_runtime.h>

typedef _Float16 f16;
typedef _Float16 f16x8 __attribute__((ext_vector_type(8)));
typedef float f32x4 __attribute__((ext_vector_type(4)));

#define BM 128
#define LDA 264   // 256 + 8 f16 pad (16B) -> conflict-free-ish ds_read_b128
#define LDF 520   // 512 + 8

__device__ __forceinline__ f16x8 zero8() {
  f16x8 v;
#pragma unroll
  for (int j = 0; j < 8; ++j) v[j] = (f16)0.f;
  return v;
}

__device__ __forceinline__ f16x8 cvt8p(const float* p) {
  float4 a = *(const float4*)p;
  float4 b = *(const float4*)(p + 4);
  f16x8 v;
  v[0] = (f16)a.x; v[1] = (f16)a.y; v[2] = (f16)a.z; v[3] = (f16)a.w;
  v[4] = (f16)b.x; v[5] = (f16)b.y; v[6] = (f16)b.z; v[7] = (f16)b.w;
  return v;
}

__device__ __forceinline__ float sigm(float x) { return 1.f / (1.f + __expf(-x)); }
__device__ __forceinline__ float tanh_(float x) {
  x = fminf(15.f, fmaxf(-15.f, x));
  float e = __expf(2.f * x);
  return 1.f - 2.f / (e + 1.f);
}

// ---------------- small utility kernels ----------------

// fp32 -> f16, 8 elems/thread, grid-stride. n must be a multiple of 8.
__global__ void k_cvt8(const float* __restrict__ x, f16* __restrict__ y, long n) {
  long i = ((long)blockIdx.x * blockDim.x + threadIdx.x) * 8;
  long stride = (long)gridDim.x * blockDim.x * 8;
  for (; i < n; i += stride) {
    *(f16x8*)(y + i) = cvt8p(x + i);
  }
}

// Wc[j][k] = sum_c Wih[j][c] * W[c][k]   (j = blockIdx.x in [0,768), k = tid in [0,256))
__global__ void k_wc(const float* __restrict__ Wih, const float* __restrict__ W,
                     f16* __restrict__ Wc) {
  int j = blockIdx.x;
  int k = threadIdx.x;
  float s = 0.f;
  for (int c = 0; c < 256; ++c) s = fmaf(Wih[j * 256 + c], W[c * 256 + k], s);
  Wc[j * 256 + k] = (f16)s;
}

// v[j] = sum_c Wih[j][c] * b[c]
__global__ void k_v(const float* __restrict__ Wih, const float* __restrict__ b,
                    float* __restrict__ v) {
  int j = blockIdx.x * blockDim.x + threadIdx.x;
  if (j < 768) {
    float s = 0.f;
    for (int c = 0; c < 256; ++c) s = fmaf(Wih[j * 256 + c], b[c], s);
    v[j] = s;
  }
}

__global__ void k_hist(const int* __restrict__ dst, int* __restrict__ cnt, int E) {
  int e = blockIdx.x * 256 + threadIdx.x;
  if (e < E) atomicAdd(&cnt[dst[e]], 1);
}

__global__ void k_scan1(const int* __restrict__ deg, int* __restrict__ rowptr,
                        int* __restrict__ bsum, int n) {
  __shared__ int buf[256];
  int i = blockIdx.x * 256 + threadIdx.x;
  int v = (i < n) ? deg[i] : 0;
  buf[threadIdx.x] = v;
  __syncthreads();
  for (int off = 1; off < 256; off <<= 1) {
    int t = 0;
    if ((int)threadIdx.x >= off) t = buf[threadIdx.x - off];
    __syncthreads();
    buf[threadIdx.x] += t;
    __syncthreads();
  }
  if (i < n) rowptr[i] = buf[threadIdx.x] - v;  // exclusive within block
  if (threadIdx.x == 255) bsum[blockIdx.x] = buf[255];
}

// single block, nb <= 1024: in-place exclusive scan of bsum
__global__ void k_scan2(int* __restrict__ bsum, int nb) {
  __shared__ int buf[1024];
  int v = ((int)threadIdx.x < nb) ? bsum[threadIdx.x] : 0;
  buf[threadIdx.x] = v;
  __syncthreads();
  for (int off = 1; off < 1024; off <<= 1) {
    int t = 0;
    if ((int)threadIdx.x >= off) t = buf[threadIdx.x - off];
    __syncthreads();
    buf[threadIdx.x] += t;
    __syncthreads();
  }
  if ((int)threadIdx.x < nb) bsum[threadIdx.x] = buf[threadIdx.x] - v;
}

__global__ void k_scan3(int* __restrict__ rowptr, const int* __restrict__ bsum,
                        int n, int E) {
  int i = blockIdx.x * 256 + threadIdx.x;
  if (i < n) rowptr[i] += bsum[blockIdx.x];
  if (i == n) rowptr[n] = E;
}

__global__ void k_fill(const int* __restrict__ src, const int* __restrict__ dst,
                       const int* __restrict__ rowptr, int* __restrict__ cnt,
                       int* __restrict__ esrc, int E) {
  int e = blockIdx.x * 256 + threadIdx.x;
  if (e < E) {
    int d = dst[e];
    int r = atomicAdd(&cnt[d], 1);
    esrc[rowptr[d] + r] = src[e];
  }
}

// ag[i,:] = sum over incoming edges of h[src,:]  (fp32 accumulate, f16 store)
// 32-lane group per node, 8 nodes / 256-thr block
__global__ void k_gather(const f16* __restrict__ h, const int* __restrict__ rowptr,
                         const int* __restrict__ esrc, f16* __restrict__ ag, int n) {
  int g = threadIdx.x >> 5, l = threadIdx.x & 31;
  int node = blockIdx.x * 8 + g;
  if (node >= n) return;
  int e0 = rowptr[node], e1 = rowptr[node + 1];
  float acc[8];
#pragma unroll
  for (int j = 0; j < 8; ++j) acc[j] = 0.f;
  for (int e = e0; e < e1; ++e) {
    int s = esrc[e];
    f16x8 hv = *(const f16x8*)(h + (long)s * 256 + l * 8);
#pragma unroll
    for (int j = 0; j < 8; ++j) acc[j] += (float)hv[j];
  }
  f16x8 o;
#pragma unroll
  for (int j = 0; j < 8; ++j) o[j] = (f16)acc[j];
  *(f16x8*)(ag + (long)node * 256 + l * 8) = o;
}

// ---------------- fused GRU kernel ----------------
// block = (row-tile rt of 128 rows) x (col-group cg of 64 h-cols); 512 threads = 8 waves
// gi = ag @ Wc^T (+deg*v + bih), gh = h @ Whh^T (+bhh); GRU elementwise -> hout (f16)
__global__ __launch_bounds__(512, 2) void k_gru(
    const f16* __restrict__ ag, const f16* __restrict__ hin,
    const f16* __restrict__ Wc, const f16* __restrict__ Whh,
    const float* __restrict__ bih, const float* __restrict__ bhh,
    const float* __restrict__ vv, const int* __restrict__ rowptr,
    f16* __restrict__ hout, int n) {
  __shared__ f16 As[BM * LDA];
  __shared__ f16 Hs[BM * LDA];
  int bx = blockIdx.x;
  int rt = bx >> 2, cg = bx & 3;
  int row0 = rt * BM;
  int tid = threadIdx.x;

  // stage A panels (ag and h) into LDS as f16, zero-pad OOB rows
  for (int c = tid; c < BM * 32; c += 512) {
    int r = c >> 5, kc = c & 31;
    int grow = row0 + r;
    f16x8 va = zero8(), vh = zero8();
    if (grow < n) {
      va = *(const f16x8*)(ag + (long)grow * 256 + kc * 8);
      vh = *(const f16x8*)(hin + (long)grow * 256 + kc * 8);
    }
    *(f16x8*)(&As[r * LDA + kc * 8]) = va;
    *(f16x8*)(&Hs[r * LDA + kc * 8]) = vh;
  }
  __syncthreads();

  int lane = tid & 63, wid = tid >> 6;
  int lr = lane & 15, kg = lane >> 4;
  int wrow = wid * 16;

  f32x4 acc[6][4];
#pragma unroll
  for (int g = 0; g < 6; ++g)
#pragma unroll
    for (int ct = 0; ct < 4; ++ct)
#pragma unroll
      for (int j = 0; j < 4; ++j) acc[g][ct][j] = 0.f;

  const f16* Ap = &As[(wrow + lr) * LDA + kg * 8];
  const f16* Hp = &Hs[(wrow + lr) * LDA + kg * 8];
  long boff = ((long)(cg * 64 + lr)) * 256 + kg * 8;
  const f16* Wcb = Wc + boff;
  const f16* Whb = Whh + boff;

#pragma unroll
  for (int ks = 0; ks < 8; ++ks) {
    f16x8 af = *(const f16x8*)(Ap + ks * 32);
    f16x8 hf = *(const f16x8*)(Hp + ks * 32);
#pragma unroll
    for (int g = 0; g < 3; ++g) {
#pragma unroll
      for (int ct = 0; ct < 4; ++ct) {
        f16x8 bf = *(const f16x8*)(Wcb + g * 65536 + ct * 4096 + ks * 32);
        acc[g][ct] = __builtin_amdgcn_mfma_f32_16x16x32_f16(af, bf, acc[g][ct], 0, 0, 0);
      }
    }
#pragma unroll
    for (int g = 0; g < 3; ++g) {
#pragma unroll
      for (int ct = 0; ct < 4; ++ct) {
        f16x8 bf = *(const f16x8*)(Whb + g * 65536 + ct * 4096 + ks * 32);
        acc[3 + g][ct] = __builtin_amdgcn_mfma_f32_16x16x32_f16(hf, bf, acc[3 + g][ct], 0, 0, 0);
      }
    }
  }

  // epilogue: GRU elementwise. C layout: col = lane&15, row = (lane>>4)*4 + reg
  float dgv[4];
#pragma unroll
  for (int rr = 0; rr < 4; ++rr) {
    int grow = row0 + wrow + kg * 4 + rr;
    dgv[rr] = (grow < n) ? (float)(rowptr[grow + 1] - rowptr[grow]) : 0.f;
  }
#pragma unroll
  for (int ct = 0; ct < 4; ++ct) {
    int gc = cg * 64 + ct * 16 + lr;  // h-col in [0,256)
    float br = bih[gc] + bhh[gc];
    float bz = bih[256 + gc] + bhh[256 + gc];
    float bin_ = bih[512 + gc];
    float bhn = bhh[512 + gc];
    float vr = vv[gc], vz = vv[256 + gc], vn = vv[512 + gc];
#pragma unroll
    for (int rr = 0; rr < 4; ++rr) {
      int lrow = wrow + kg * 4 + rr;
      float sr = acc[0][ct][rr] + acc[3][ct][rr] + br + dgv[rr] * vr;
      float sz = acc[1][ct][rr] + acc[4][ct][rr] + bz + dgv[rr] * vz;
      float r = sigm(sr);
      float z = sigm(sz);
      float xn = acc[2][ct][rr] + bin_ + dgv[rr] * vn + r * (acc[5][ct][rr] + bhn);
      float nn = tanh_(xn);
      float hold = (float)Hs[lrow * LDA + gc];
      Hs[lrow * LDA + gc] = (f16)((1.f - z) * nn + z * hold);
    }
  }
  __syncthreads();
  // coalesced copy-out of this block's 64-col slice
  for (int c = tid; c < BM * 8; c += 512) {
    int r = c >> 3, q = c & 7;
    int grow = row0 + r;
    if (grow < n)
      *(f16x8*)(hout + (long)grow * 256 + cg * 64 + q * 8) =
          *(const f16x8*)(&Hs[r * LDA + cg * 64 + q * 8]);
  }
}

// ---------------- fused concat-linear: out = [hb | base] @ w^T + bias ----------------
// block = 128 rows x 256 cols, K = 512; in-place safe (block reads only its own rows)
__global__ __launch_bounds__(512, 2) void k_fn(
    const f16* __restrict__ hb, const float* __restrict__ base,
    const f16* __restrict__ w, const float* __restrict__ bias,
    float* __restrict__ out, int n) {
  __shared__ f16 Fs[BM * LDF];
  int row0 = blockIdx.x * BM;
  int tid = threadIdx.x;
  for (int c = tid; c < BM * 64; c += 512) {
    int r = c >> 6, q = c & 63;
    int grow = row0 + r;
    f16x8 v = zero8();
    if (grow < n) {
      if (q < 32)
        v = *(const f16x8*)(hb + (long)grow * 256 + q * 8);
      else
        v = cvt8p(base + (long)grow * 256 + (q - 32) * 8);
    }
    *(f16x8*)(&Fs[r * LDF + q * 8]) = v;
  }
  __syncthreads();

  int lane = tid & 63, wid = tid >> 6;
  int lr = lane & 15, kg = lane >> 4;
  int wrow = wid * 16;
  f32x4 acc[16];
#pragma unroll
  for (int ct = 0; ct < 16; ++ct)
#pragma unroll
    for (int j = 0; j < 4; ++j) acc[ct][j] = 0.f;

  const f16* Ap = &Fs[(wrow + lr) * LDF + kg * 8];
#pragma unroll
  for (int ks = 0; ks < 16; ++ks) {
    f16x8 af = *(const f16x8*)(Ap + ks * 32);
#pragma unroll
    for (int ct = 0; ct < 16; ++ct) {
      f16x8 bf = *(const f16x8*)(w + (long)(ct * 16 + lr) * 512 + ks * 32 + kg * 8);
      acc[ct] = __builtin_amdgcn_mfma_f32_16x16x32_f16(af, bf, acc[ct], 0, 0, 0);
    }
  }
#pragma unroll
  for (int ct = 0; ct < 16; ++ct) {
    int col = ct * 16 + lr;
    float bb = bias[col];
#pragma unroll
    for (int rr = 0; rr < 4; ++rr) {
      int grow = row0 + wrow + kg * 4 + rr;
      if (grow < n) out[(long)grow * 256 + col] = acc[ct][rr] + bb;
    }
  }
}

// ---------------- launch ----------------
extern "C" void kernel_launch(void* const* d_in, const int* in_sizes, int n_in,
                              void* d_out, int out_size, void* d_ws, size_t ws_size,
                              hipStream_t stream) {
  const float* nodes = (const float*)d_in[0];
  const int* asrc = (const int*)d_in[1];
  const int* adst = (const int*)d_in[2];
  const int* csrc = (const int*)d_in[3];
  const int* cdst = (const int*)d_in[4];
  const float* W_ast = (const float*)d_in[5];
  const float* b_ast = (const float*)d_in[6];
  const float* Wih_a = (const float*)d_in[7];
  const float* Whh_a = (const float*)d_in[8];
  const float* bih_a = (const float*)d_in[9];
  const float* bhh_a = (const float*)d_in[10];
  const float* w1 = (const float*)d_in[11];
  const float* b1 = (const float*)d_in[12];
  const float* W_cpg = (const float*)d_in[13];
  const float* b_cpg = (const float*)d_in[14];
  const float* Wih_c = (const float*)d_in[15];
  const float* Whh_c = (const float*)d_in[16];
  const float* bih_c = (const float*)d_in[17];
  const float* bhh_c = (const float*)d_in[18];
  const float* w2 = (const float*)d_in[19];
  const float* b2 = (const float*)d_in[20];
  float* out = (float*)d_out;

  const int N = in_sizes[0] / 256;  // 150000
  const int EA = in_sizes[1];       // 300000
  const int EC = in_sizes[3];       // 250000
  const long ND = (long)N * 256;

  // carve workspace
  char* ws = (char*)d_ws;
  size_t off = 0;
  auto carve = [&](size_t bytes) -> char* {
    char* p = ws + off;
    off += (bytes + 255) & ~(size_t)255;
    return p;
  };
  f16* h0 = (f16*)carve(ND * 2);
  f16* h1 = (f16*)carve(ND * 2);
  f16* ag = (f16*)carve(ND * 2);
  f16* WcA = (f16*)carve(768 * 256 * 2);
  f16* WhA = (f16*)carve(768 * 256 * 2);
  f16* WcC = (f16*)carve(768 * 256 * 2);
  f16* WhC = (f16*)carve(768 * 256 * 2);
  f16* w1h = (f16*)carve(512 * 256 * 2);
  f16* w2h = (f16*)carve(512 * 256 * 2);
  float* vA = (float*)carve(768 * 4);
  float* vC = (float*)carve(768 * 4);
  int* rowptr = (int*)carve((size_t)(N + 1) * 4);
  int* cnt = (int*)carve((size_t)N * 4);
  int* esrc = (int*)carve((size_t)(EA > EC ? EA : EC) * 4);
  int* bsum = (int*)carve(1024 * 4);
  (void)ws_size; (void)n_in; (void)out_size;

  const int NBLK = (N + BM - 1) / BM;       // 1172
  const int SBLK = (N + 255) / 256;         // 586
  auto cvt = [&](const float* x, f16* y, long n) {
    int blocks = (int)((n / 8 + 255) / 256);
    if (blocks > 2048) blocks = 2048;
    k_cvt8<<<blocks, 256, 0, stream>>>(x, y, n);
  };

  // weight prep
  k_wc<<<768, 256, 0, stream>>>(Wih_a, W_ast, WcA);
  k_wc<<<768, 256, 0, stream>>>(Wih_c, W_cpg, WcC);
  k_v<<<3, 256, 0, stream>>>(Wih_a, b_ast, vA);
  k_v<<<3, 256, 0, stream>>>(Wih_c, b_cpg, vC);
  cvt(Whh_a, WhA, 768 * 256);
  cvt(Whh_c, WhC, 768 * 256);
  cvt(w1, w1h, 512 * 256);
  cvt(w2, w2h, 512 * 256);
  cvt(nodes, h0, ND);

  auto run_branch = [&](const int* src, const int* dst, int E, const f16* Wc,
                        const f16* Whh, const float* bih, const float* bhh,
                        const float* v) {
    // CSR build (by dst)
    hipMemsetAsync(cnt, 0, (size_t)N * 4, stream);
    k_hist<<<(E + 255) / 256, 256, 0, stream>>>(dst, cnt, E);
    k_scan1<<<SBLK, 256, 0, stream>>>(cnt, rowptr, bsum, N);
    k_scan2<<<1, 1024, 0, stream>>>(bsum, SBLK);
    k_scan3<<<SBLK, 256, 0, stream>>>(rowptr, bsum, N, E);
    hipMemsetAsync(cnt, 0, (size_t)N * 4, stream);
    k_fill<<<(E + 255) / 256, 256, 0, stream>>>(src, dst, rowptr, cnt, esrc, E);
    // step 1: h0 -> h1
    k_gather<<<(N + 7) / 8, 256, 0, stream>>>(h0, rowptr, esrc, ag, N);
    k_gru<<<NBLK * 4, 512, 0, stream>>>(ag, h0, Wc, Whh, bih, bhh, v, rowptr, h1, N);
    // step 2: h1 -> h0
    k_gather<<<(N + 7) / 8, 256, 0, stream>>>(h1, rowptr, esrc, ag, N);
    k_gru<<<NBLK * 4, 512, 0, stream>>>(ag, h1, Wc, Whh, bih, bhh, v, rowptr, h0, N);
  };

  // AST branch
  run_branch(asrc, adst, EA, WcA, WhA, bih_a, bhh_a, vA);
  // hiddens = [h_ast | nodes] @ w1^T + b1  -> d_out (fp32)
  k_fn<<<NBLK, 512, 0, stream>>>(h0, nodes, w1h, b1, out, N);
  // CPG branch, starting from hiddens
  cvt(out, h0, ND);
  run_branch(csrc, cdst, EC, WcC, WhC, bih_c, bhh_c, vC);
  // logits = [h_cpg | hiddens] @ w2^T + b2 -> d_out (in-place safe per row-block)
  k_fn<<<NBLK, 512, 0, stream>>>(h0, out, w2h, b2, out, N);
}

// Round 3
// 1869.017 us; speedup vs baseline: 2.6681x; 2.6681x over previous
//
#include <hip/hip_runtime.h>

typedef _Float16 f16;
typedef _Float16 f16x8 __attribute__((ext_vector_type(8)));
typedef float f32x16 __attribute__((ext_vector_type(16)));

#define BM 128

__device__ __forceinline__ f16x8 zero8() {
  f16x8 v;
#pragma unroll
  for (int j = 0; j < 8; ++j) v[j] = (f16)0.f;
  return v;
}

__device__ __forceinline__ f16x8 cvt8p(const float* p) {
  float4 a = *(const float4*)p;
  float4 b = *(const float4*)(p + 4);
  f16x8 v;
  v[0] = (f16)a.x; v[1] = (f16)a.y; v[2] = (f16)a.z; v[3] = (f16)a.w;
  v[4] = (f16)b.x; v[5] = (f16)b.y; v[6] = (f16)b.z; v[7] = (f16)b.w;
  return v;
}

__device__ __forceinline__ void gload16(const void* g, void* l) {
  __builtin_amdgcn_global_load_lds((const __attribute__((address_space(1))) unsigned int*)g,
                                   (__attribute__((address_space(3))) unsigned int*)l, 16, 0, 0);
}

__device__ __forceinline__ float sigm(float x) { return 1.f / (1.f + __expf(-x)); }
__device__ __forceinline__ float tanh_(float x) {
  x = fminf(15.f, fmaxf(-15.f, x));
  float e = __expf(2.f * x);
  return 1.f - 2.f / (e + 1.f);
}

// ---------------- small utility kernels ----------------

__global__ void k_cvt8(const float* __restrict__ x, f16* __restrict__ y, long n) {
  long i = ((long)blockIdx.x * blockDim.x + threadIdx.x) * 8;
  long stride = (long)gridDim.x * blockDim.x * 8;
  for (; i < n; i += stride) *(f16x8*)(y + i) = cvt8p(x + i);
}

// Wc = Wih·W fused, written in the k_gru LDS-image layout:
// region (cg,chunk) of 49152B = [side][192 rows][64 k] f16, XOR-swizzled.
__global__ void k_wc2(const float* __restrict__ Wih, const float* __restrict__ W,
                      f16* __restrict__ dst) {
  int j = blockIdx.x;   // 0..767: output row of Wc (gate*256 + hcol)
  int k = threadIdx.x;  // 0..255
  float s = 0.f;
  for (int c = 0; c < 256; ++c) s = fmaf(Wih[j * 256 + c], W[c * 256 + k], s);
  int g = j >> 8, col = j & 255, cg = col >> 6, cid = col & 63;
  int r = g * 64 + cid, ch = k >> 6, kl = k & 63;
  dst[(size_t)(cg * 4 + ch) * 24576 + r * 64 + (kl ^ ((r & 7) << 3))] = (f16)s;
}

// Whh -> same layout, side-1 half (offset 12288 f16 within each region)
__global__ void k_whh2(const float* __restrict__ Whh, f16* __restrict__ dst) {
  int j = blockIdx.x;
  int k = threadIdx.x;
  float s = Whh[j * 256 + k];
  int g = j >> 8, col = j & 255, cg = col >> 6, cid = col & 63;
  int r = g * 64 + cid, ch = k >> 6, kl = k & 63;
  dst[(size_t)(cg * 4 + ch) * 24576 + 12288 + r * 64 + (kl ^ ((r & 7) << 3))] = (f16)s;
}

// w1/w2 [256][512] -> k_fn LDS image: [chunk 4][256 rows][128 k] f16 swizzled
__global__ void k_prepw(const float* __restrict__ w, f16* __restrict__ dst) {
  int j = blockIdx.x;  // output row 0..255
  for (int k = threadIdx.x; k < 512; k += 256) {
    int c = k >> 7, kl = k & 127;
    dst[(size_t)c * 32768 + j * 128 + (kl ^ ((j & 7) << 3))] = (f16)w[j * 512 + k];
  }
}

// v[j] = sum_c Wih[j][c] * b[c]
__global__ void k_v(const float* __restrict__ Wih, const float* __restrict__ b,
                    float* __restrict__ v) {
  int j = blockIdx.x * blockDim.x + threadIdx.x;
  if (j < 768) {
    float s = 0.f;
    for (int c = 0; c < 256; ++c) s = fmaf(Wih[j * 256 + c], b[c], s);
    v[j] = s;
  }
}

__global__ void k_hist(const int* __restrict__ dst, int* __restrict__ cnt, int E) {
  int e = blockIdx.x * 256 + threadIdx.x;
  if (e < E) atomicAdd(&cnt[dst[e]], 1);
}

__global__ void k_scan1(const int* __restrict__ deg, int* __restrict__ rowptr,
                        int* __restrict__ bsum, int n) {
  __shared__ int buf[256];
  int i = blockIdx.x * 256 + threadIdx.x;
  int v = (i < n) ? deg[i] : 0;
  buf[threadIdx.x] = v;
  __syncthreads();
  for (int off = 1; off < 256; off <<= 1) {
    int t = 0;
    if ((int)threadIdx.x >= off) t = buf[threadIdx.x - off];
    __syncthreads();
    buf[threadIdx.x] += t;
    __syncthreads();
  }
  if (i < n) rowptr[i] = buf[threadIdx.x] - v;
  if (threadIdx.x == 255) bsum[blockIdx.x] = buf[255];
}

__global__ void k_scan2(int* __restrict__ bsum, int nb) {
  __shared__ int buf[1024];
  int v = ((int)threadIdx.x < nb) ? bsum[threadIdx.x] : 0;
  buf[threadIdx.x] = v;
  __syncthreads();
  for (int off = 1; off < 1024; off <<= 1) {
    int t = 0;
    if ((int)threadIdx.x >= off) t = buf[threadIdx.x - off];
    __syncthreads();
    buf[threadIdx.x] += t;
    __syncthreads();
  }
  if ((int)threadIdx.x < nb) bsum[threadIdx.x] = buf[threadIdx.x] - v;
}

__global__ void k_scan3(int* __restrict__ rowptr, const int* __restrict__ bsum,
                        int n, int E) {
  int i = blockIdx.x * 256 + threadIdx.x;
  if (i < n) rowptr[i] += bsum[blockIdx.x];
  if (i == n) rowptr[n] = E;
}

__global__ void k_fill(const int* __restrict__ src, const int* __restrict__ dst,
                       const int* __restrict__ rowptr, int* __restrict__ cnt,
                       int* __restrict__ esrc, int E) {
  int e = blockIdx.x * 256 + threadIdx.x;
  if (e < E) {
    int d = dst[e];
    int r = atomicAdd(&cnt[d], 1);
    esrc[rowptr[d] + r] = src[e];
  }
}

__global__ void k_gather(const f16* __restrict__ h, const int* __restrict__ rowptr,
                         const int* __restrict__ esrc, f16* __restrict__ ag, int n) {
  int g = threadIdx.x >> 5, l = threadIdx.x & 31;
  int node = blockIdx.x * 8 + g;
  if (node >= n) return;
  int e0 = rowptr[node], e1 = rowptr[node + 1];
  float acc[8];
#pragma unroll
  for (int j = 0; j < 8; ++j) acc[j] = 0.f;
  for (int e = e0; e < e1; ++e) {
    int s = esrc[e];
    f16x8 hv = *(const f16x8*)(h + (long)s * 256 + l * 8);
#pragma unroll
    for (int j = 0; j < 8; ++j) acc[j] += (float)hv[j];
  }
  f16x8 o;
#pragma unroll
  for (int j = 0; j < 8; ++j) o[j] = (f16)acc[j];
  *(f16x8*)(ag + (long)node * 256 + l * 8) = o;
}

// ---------------- fused GRU kernel v2 ----------------
// Block = 128 rows x (cg: 64 h-cols). 8 waves: wid<4 -> gi (A=ag), wid>=4 -> gh (A=h).
// A (32 rows x K=256) in registers; B (weights, pre-swizzled) double-buffered in LDS
// via global_load_lds, 4 K-chunks of 64. 32x32x16 MFMA, 6 acc tiles/wave.
__global__ __launch_bounds__(512, 2) void k_gru(
    const f16* __restrict__ ag, const f16* __restrict__ hin,
    const f16* __restrict__ wprep, const float* __restrict__ bih,
    const float* __restrict__ bhh, const float* __restrict__ vv,
    const int* __restrict__ rowptr, f16* __restrict__ hout, int n) {
  __shared__ unsigned char SM[98304 + 16384 + 512];
  f16* Xs = (f16*)(SM + 98304);            // h_old / h' slice [128][64]
  float* Ds = (float*)(SM + 98304 + 16384);  // deg[128]
  int bx = blockIdx.x;
  int rt = bx >> 2, cg = bx & 3;
  int row0 = rt * BM;
  int tid = threadIdx.x;
  int lane = tid & 63, wid = tid >> 6;
  int l31 = lane & 31, hi = lane >> 5;
  int side = wid >> 2, wg = wid & 3;
  int wrow = wg * 32;
  const unsigned char* wbytes = (const unsigned char*)wprep;

  // stage chunk 0 (oldest in vmcnt queue)
  {
    const unsigned char* s0 = wbytes + (size_t)(cg * 4 + 0) * 49152 + wid * 6144;
    unsigned char* d0 = SM + wid * 6144;
#pragma unroll
    for (int i = 0; i < 6; ++i) gload16(s0 + i * 1024 + lane * 16, d0 + i * 1024);
  }

  // A-fragments: this wave's 32 rows x 256 K of its matrix, in registers
  const f16* Amat = side ? hin : ag;
  int arow = row0 + wrow + l31;
  bool aok = arow < n;
  const f16* abase = Amat + (size_t)arow * 256 + hi * 8;
  f16x8 areg[16];
#pragma unroll
  for (int c = 0; c < 4; ++c)
#pragma unroll
    for (int ks = 0; ks < 4; ++ks)
      areg[c * 4 + ks] = aok ? *(const f16x8*)(abase + c * 64 + ks * 16) : zero8();

  // stage h_old slice + deg into LDS
  for (int e = tid; e < 1024; e += 512) {
    int r = e >> 3, q = e & 7;
    int grow = row0 + r;
    f16x8 v = (grow < n) ? *(const f16x8*)(hin + (size_t)grow * 256 + cg * 64 + q * 8)
                         : zero8();
    *(f16x8*)(Xs + r * 64 + q * 8) = v;
  }
  if (tid < 128) {
    int grow = row0 + tid;
    Ds[tid] = (grow < n) ? (float)(rowptr[grow + 1] - rowptr[grow]) : 0.f;
  }
  __syncthreads();

  f32x16 acc[6];
#pragma unroll
  for (int t = 0; t < 6; ++t)
#pragma unroll
    for (int j = 0; j < 16; ++j) acc[t][j] = 0.f;

  for (int c = 0; c < 4; ++c) {
    if (c < 3) {  // prefetch next chunk into other buffer
      const unsigned char* s1 = wbytes + (size_t)(cg * 4 + c + 1) * 49152 + wid * 6144;
      unsigned char* d1 = SM + ((c + 1) & 1) * 49152 + wid * 6144;
#pragma unroll
      for (int i = 0; i < 6; ++i) gload16(s1 + i * 1024 + lane * 16, d1 + i * 1024);
    }
    const unsigned char* Bb = SM + (c & 1) * 49152 + side * 24576;
#pragma unroll
    for (int ks = 0; ks < 4; ++ks) {
      f16x8 a = areg[c * 4 + ks];
#pragma unroll
      for (int t = 0; t < 6; ++t) {
        int r = t * 32 + l31;
        f16x8 b = *(const f16x8*)(Bb + r * 128 + ((ks * 32 + hi * 16) ^ ((r & 7) << 4)));
        acc[t] = __builtin_amdgcn_mfma_f32_32x32x16_f16(a, b, acc[t], 0, 0, 0);
      }
    }
    __syncthreads();  // drains stage c+1; all waves done reading buffer c
  }

  // exchange: gh-waves dump acc into (now free) B buffer
  float* Ex = (float*)SM;
  if (side == 1) {
#pragma unroll
    for (int t = 0; t < 6; ++t)
#pragma unroll
      for (int rg = 0; rg < 16; ++rg)
        Ex[wg * 6144 + t * 1024 + rg * 64 + lane] = acc[t][rg];
  }
  __syncthreads();

  if (side == 0) {
    const float* gh = Ex + wg * 6144;
#pragma unroll
    for (int half = 0; half < 2; ++half) {
      int col = half * 32 + l31;
      int gcol = cg * 64 + col;
      float br = bih[gcol] + bhh[gcol];
      float bz = bih[256 + gcol] + bhh[256 + gcol];
      float bi_n = bih[512 + gcol];
      float bh_n = bhh[512 + gcol];
      float vr = vv[gcol], vz = vv[256 + gcol], vn = vv[512 + gcol];
#pragma unroll
      for (int rg = 0; rg < 16; ++rg) {
        int crow = (rg & 3) + 8 * (rg >> 2) + 4 * hi;
        int rl = wrow + crow;
        float dg = Ds[rl];
        float ghr = gh[(0 + half) * 1024 + rg * 64 + lane];
        float ghz = gh[(2 + half) * 1024 + rg * 64 + lane];
        float ghn = gh[(4 + half) * 1024 + rg * 64 + lane];
        float sr = acc[0 + half][rg] + ghr + br + dg * vr;
        float sz = acc[2 + half][rg] + ghz + bz + dg * vz;
        float r = sigm(sr), z = sigm(sz);
        float xn = acc[4 + half][rg] + bi_n + dg * vn + r * (ghn + bh_n);
        float nn = tanh_(xn);
        float hold = (float)Xs[rl * 64 + col];
        Xs[rl * 64 + col] = (f16)((1.f - z) * nn + z * hold);
      }
    }
  }
  __syncthreads();

  // coalesced copy-out
  for (int e = tid; e < 1024; e += 512) {
    int r = e >> 3, q = e & 7;
    int grow = row0 + r;
    if (grow < n)
      *(f16x8*)(hout + (size_t)grow * 256 + cg * 64 + q * 8) =
          *(const f16x8*)(Xs + r * 64 + q * 8);
  }
}

// ---------------- fused concat-linear v2: out = [hb | base] @ w^T + bias ----------
// Block = 128 rows x 256 cols, K=512 in 4 chunks of 128. 8 waves: (wid&3)=rowgrp,
// (wid>>2)=col half. B in single 64KB LDS buffer (2 blocks/CU), A-chunk in regs.
__global__ __launch_bounds__(512, 4) void k_fn(
    const f16* __restrict__ hb, const float* __restrict__ base,
    const f16* __restrict__ wp, const float* __restrict__ bias,
    float* __restrict__ out, int n) {
  __shared__ unsigned char SM[65536];
  int row0 = blockIdx.x * BM;
  int tid = threadIdx.x;
  int lane = tid & 63, wid = tid >> 6;
  int l31 = lane & 31, hi = lane >> 5;
  int wg = wid & 3, ch = wid >> 2;
  int wrow = wg * 32;
  int arow = row0 + wrow + l31;
  bool aok = arow < n;
  const unsigned char* wbytes = (const unsigned char*)wp;

  f32x16 acc[4];
#pragma unroll
  for (int t = 0; t < 4; ++t)
#pragma unroll
    for (int j = 0; j < 16; ++j) acc[t][j] = 0.f;

  for (int c = 0; c < 4; ++c) {
    if (c) __syncthreads();  // previous chunk fully consumed
    const unsigned char* s0 = wbytes + (size_t)c * 65536 + wid * 8192;
    unsigned char* d0 = SM + wid * 8192;
#pragma unroll
    for (int i = 0; i < 8; ++i) gload16(s0 + i * 1024 + lane * 16, d0 + i * 1024);
    // A chunk (overlaps with stage flight time)
    f16x8 areg[8];
#pragma unroll
    for (int ks = 0; ks < 8; ++ks) {
      int kglob = c * 128 + ks * 16 + hi * 8;
      if (!aok)
        areg[ks] = zero8();
      else if (kglob < 256)
        areg[ks] = *(const f16x8*)(hb + (size_t)arow * 256 + kglob);
      else
        areg[ks] = cvt8p(base + (size_t)arow * 256 + (kglob - 256));
    }
    __syncthreads();  // stage landed
#pragma unroll
    for (int ks = 0; ks < 8; ++ks) {
#pragma unroll
      for (int t = 0; t < 4; ++t) {
        int r = ch * 128 + t * 32 + l31;
        f16x8 b = *(const f16x8*)(SM + r * 256 + ((ks * 32 + hi * 16) ^ ((r & 7) << 4)));
        acc[t] = __builtin_amdgcn_mfma_f32_32x32x16_f16(areg[ks], b, acc[t], 0, 0, 0);
      }
    }
  }

#pragma unroll
  for (int t = 0; t < 4; ++t) {
    int col = ch * 128 + t * 32 + l31;
    float bb = bias[col];
#pragma unroll
    for (int rg = 0; rg < 16; ++rg) {
      int grow = row0 + wrow + (rg & 3) + 8 * (rg >> 2) + 4 * hi;
      if (grow < n) out[(size_t)grow * 256 + col] = acc[t][rg] + bb;
    }
  }
}

// ---------------- launch ----------------
extern "C" void kernel_launch(void* const* d_in, const int* in_sizes, int n_in,
                              void* d_out, int out_size, void* d_ws, size_t ws_size,
                              hipStream_t stream) {
  const float* nodes = (const float*)d_in[0];
  const int* asrc = (const int*)d_in[1];
  const int* adst = (const int*)d_in[2];
  const int* csrc = (const int*)d_in[3];
  const int* cdst = (const int*)d_in[4];
  const float* W_ast = (const float*)d_in[5];
  const float* Wih_a = (const float*)d_in[7];
  const float* Whh_a = (const float*)d_in[8];
  const float* bih_a = (const float*)d_in[9];
  const float* bhh_a = (const float*)d_in[10];
  const float* w1 = (const float*)d_in[11];
  const float* b1 = (const float*)d_in[12];
  const float* W_cpg = (const float*)d_in[13];
  const float* Wih_c = (const float*)d_in[15];
  const float* Whh_c = (const float*)d_in[16];
  const float* bih_c = (const float*)d_in[17];
  const float* bhh_c = (const float*)d_in[18];
  const float* w2 = (const float*)d_in[19];
  const float* b2 = (const float*)d_in[20];
  const float* b_ast = (const float*)d_in[6];
  const float* b_cpg = (const float*)d_in[14];
  float* out = (float*)d_out;

  const int N = in_sizes[0] / 256;  // 150000
  const int EA = in_sizes[1];       // 300000
  const int EC = in_sizes[3];       // 250000
  const long ND = (long)N * 256;

  char* ws = (char*)d_ws;
  size_t off = 0;
  auto carve = [&](size_t bytes) -> char* {
    char* p = ws + off;
    off += (bytes + 255) & ~(size_t)255;
    return p;
  };
  f16* h0 = (f16*)carve(ND * 2);
  f16* h1 = (f16*)carve(ND * 2);
  f16* ag = (f16*)carve(ND * 2);
  f16* wpA = (f16*)carve(786432);   // 4cg x 4chunk x 49152B (Wc|Whh, swizzled)
  f16* wpC = (f16*)carve(786432);
  f16* w1p = (f16*)carve(262144);   // 4chunk x 65536B
  f16* w2p = (f16*)carve(262144);
  float* vA = (float*)carve(768 * 4);
  float* vC = (float*)carve(768 * 4);
  int* rowptr = (int*)carve((size_t)(N + 1) * 4);
  int* cnt = (int*)carve((size_t)N * 4);
  int* esrc = (int*)carve((size_t)(EA > EC ? EA : EC) * 4);
  int* bsum = (int*)carve(1024 * 4);
  (void)ws_size; (void)n_in; (void)out_size;

  const int NBLK = (N + BM - 1) / BM;  // 1172
  const int SBLK = (N + 255) / 256;    // 586
  auto cvt = [&](const float* x, f16* y, long n) {
    int blocks = (int)((n / 8 + 255) / 256);
    if (blocks > 2048) blocks = 2048;
    k_cvt8<<<blocks, 256, 0, stream>>>(x, y, n);
  };

  // weight prep (swizzled LDS-image layouts)
  k_wc2<<<768, 256, 0, stream>>>(Wih_a, W_ast, wpA);
  k_wc2<<<768, 256, 0, stream>>>(Wih_c, W_cpg, wpC);
  k_whh2<<<768, 256, 0, stream>>>(Whh_a, wpA);
  k_whh2<<<768, 256, 0, stream>>>(Whh_c, wpC);
  k_prepw<<<256, 256, 0, stream>>>(w1, w1p);
  k_prepw<<<256, 256, 0, stream>>>(w2, w2p);
  k_v<<<3, 256, 0, stream>>>(Wih_a, b_ast, vA);
  k_v<<<3, 256, 0, stream>>>(Wih_c, b_cpg, vC);
  cvt(nodes, h0, ND);

  auto run_branch = [&](const int* src, const int* dst, int E, const f16* wprep,
                        const float* bih, const float* bhh, const float* v) {
    hipMemsetAsync(cnt, 0, (size_t)N * 4, stream);
    k_hist<<<(E + 255) / 256, 256, 0, stream>>>(dst, cnt, E);
    k_scan1<<<SBLK, 256, 0, stream>>>(cnt, rowptr, bsum, N);
    k_scan2<<<1, 1024, 0, stream>>>(bsum, SBLK);
    k_scan3<<<SBLK, 256, 0, stream>>>(rowptr, bsum, N, E);
    hipMemsetAsync(cnt, 0, (size_t)N * 4, stream);
    k_fill<<<(E + 255) / 256, 256, 0, stream>>>(src, dst, rowptr, cnt, esrc, E);
    k_gather<<<(N + 7) / 8, 256, 0, stream>>>(h0, rowptr, esrc, ag, N);
    k_gru<<<NBLK * 4, 512, 0, stream>>>(ag, h0, wprep, bih, bhh, v, rowptr, h1, N);
    k_gather<<<(N + 7) / 8, 256, 0, stream>>>(h1, rowptr, esrc, ag, N);
    k_gru<<<NBLK * 4, 512, 0, stream>>>(ag, h1, wprep, bih, bhh, v, rowptr, h0, N);
  };

  run_branch(asrc, adst, EA, wpA, bih_a, bhh_a, vA);
  k_fn<<<NBLK, 512, 0, stream>>>(h0, nodes, w1p, b1, out, N);
  cvt(out, h0, ND);
  run_branch(csrc, cdst, EC, wpC, bih_c, bhh_c, vC);
  k_fn<<<NBLK, 512, 0, stream>>>(h0, out, w2p, b2, out, N);
}